// Round 3
// baseline (259.887 us; speedup 1.0000x reference)
//
#include <hip/hip_runtime.h>

#define NROWS 8192
#define HALF_N 4096
#define DIM 512
#define INV_T 10.0f
#define NRB 64              // number of 128-row blocks
#define NBLOCKS 2080        // 64*65/2 upper-triangle block pairs

typedef __attribute__((ext_vector_type(4))) float f32x4;
typedef __attribute__((ext_vector_type(4))) int i32x4;
typedef __attribute__((ext_vector_type(8))) int i32x8;

#define SCALE_ONE 0x7F7F7F7F   // E8M0 127 in every byte -> scale = 1.0

// async 16B global -> LDS (DMA). LDS dest is wave-uniform base + lane*16.
__device__ __forceinline__ void async16(const void* g, void* l) {
  __builtin_amdgcn_global_load_lds(
      (const __attribute__((address_space(1))) unsigned int*)g,
      (__attribute__((address_space(3))) unsigned int*)l, 16, 0, 0);
}

// Kernel 1: L2-normalize rows of [f1;f2] -> fp8 e4m3, written TWICE for the
// K=128 scaled-MFMA consumption pattern (lane needs 32 CONTIGUOUS k bytes):
//  Fb: plain row-major — the B/LDS copy.
//  Fa: fragment-major — panel p = row>>4 is 8 KB laid out as
//      [c32=0..15][h=0..1][row&15][16B], where c32 is the 32-byte k-chunk
//      (k in [c32*32, c32*32+32)) and h its 16B half. A-fragment loads in
//      the GEMM become coalesced global b128 (quarter-wave = 256 B contig).
__global__ __launch_bounds__(256) void norm_cast_k(
    const float* __restrict__ f1, const float* __restrict__ f2,
    unsigned char* __restrict__ Fa, unsigned char* __restrict__ Fb,
    float* __restrict__ rowsum, float* __restrict__ out) {
  int wave = threadIdx.x >> 6;
  int lane = threadIdx.x & 63;
  int row = blockIdx.x * 4 + wave;
  const float* src = (row < HALF_N) ? (f1 + (size_t)row * DIM)
                                    : (f2 + (size_t)(row - HALF_N) * DIM);
  const float4* p = reinterpret_cast<const float4*>(src + lane * 8);
  float4 v0 = p[0];
  float4 v1 = p[1];
  float ss = v0.x*v0.x + v0.y*v0.y + v0.z*v0.z + v0.w*v0.w
           + v1.x*v1.x + v1.y*v1.y + v1.z*v1.z + v1.w*v1.w;
  #pragma unroll
  for (int off = 1; off < 64; off <<= 1) ss += __shfl_xor(ss, off);
  float scale = 1.0f / fmaxf(sqrtf(ss), 1e-12f);
  int lo = __builtin_amdgcn_cvt_pk_fp8_f32(v0.x * scale, v0.y * scale, 0, false);
  lo = __builtin_amdgcn_cvt_pk_fp8_f32(v0.z * scale, v0.w * scale, lo, true);
  int hi = __builtin_amdgcn_cvt_pk_fp8_f32(v1.x * scale, v1.y * scale, 0, false);
  hi = __builtin_amdgcn_cvt_pk_fp8_f32(v1.z * scale, v1.w * scale, hi, true);
  int2 val = make_int2(lo, hi);   // 8 fp8 bytes, k = lane*8 .. lane*8+7
  // Fb: plain row-major
  *reinterpret_cast<int2*>(Fb + (size_t)row * DIM + lane * 8) = val;
  // Fa: fragment-major. k-unit U = lane (8 bytes): c32 = U>>2, half = (U>>1)&1,
  // 8B slot = U&1.
  *reinterpret_cast<int2*>(Fa + (size_t)(row >> 4) * 8192 + (lane >> 2) * 512 +
                           ((lane >> 1) & 1) * 256 + (row & 15) * 16 +
                           (lane & 1) * 8) = val;
  if (lane == 0) rowsum[row] = 0.0f;
  if (blockIdx.x == 0 && threadIdx.x == 0) out[0] = 0.0f;
}

// Kernel 2: symmetric upper-triangle sim GEMM using MX-scaled fp8 MFMA
// (mfma_f32_16x16x128_f8f6f4, unit E8M0 scales -> numerically identical to
// plain e4m3 matmul but 2x the MFMA rate and HALF the K-rounds: 4 x BK=128).
// B staged via global_load_lds (16 x 1KB insts/round) into a 128x128B LDS
// tile with 16B-chunk XOR swizzle phys = c ^ (rc&7); swizzle applied on the
// DMA's GLOBAL source, LDS dest linear. A fragments loaded DIRECTLY from
// global (Fa fragment-major, coalesced, L2-resident), merged into i32x8
// BEFORE the drain barrier so their latency overlaps the DMA.
//
// REGISTER-PRESSURE DISCIPLINE (R2 post-mortem): __launch_bounds__(256,3)
// caps the unified file at ~170 regs/thread. R1/R2 kept af[4](32) + bfv[4]
// (32) + acc(64) + addr(~24) + transients live simultaneously = ~170 ->
// allocator spilled the A fragments across the barrier = 272 MB/launch of
// scratch writes (the observed WRITE_SIZE) and MfmaUtil 3.4%. Fix: u-outer
// MFMA loop so only ONE B fragment (8 regs) is live at a time, A merged to
// av[4] once, boff computed inline. Peak ~134 regs.
__global__ __launch_bounds__(256, 3) void sym_gemm_k(
    const unsigned char* __restrict__ Fa, const unsigned char* __restrict__ Fb,
    float* __restrict__ rowsum, float* __restrict__ pairsim) {
  // XCD-contiguous remap: each XCD (bx%8) gets a contiguous 260-block range
  int bx = blockIdx.x;
  int gbx = (bx & 7) * (NBLOCKS / 8) + (bx >> 3);
  int rb = 0, rem = gbx;
  while (rem >= NRB - rb) { rem -= NRB - rb; ++rb; }
  const int cb = rb + rem;
  const int row0 = rb * 128, col0 = cb * 128;

  const int tid = threadIdx.x;
  const int wave = tid >> 6;
  const int lane = tid & 63;
  const int quad = lane >> 4;
  const int colid = lane & 15;
  const int wr0 = (wave >> 1) * 64;   // wave's row offset within tile
  const int wc0 = (wave & 1) * 64;    // wave's col offset within tile

  // B LDS tile: 128 rows x 128 k-bytes; 8 x 16B chunks per row, phys = c^(rc&7).
  __shared__ __align__(16) unsigned char Blds[128 * 128];
  __shared__ float redrow[128];
  __shared__ float redcol[128];

  if (tid < 128) { redrow[tid] = 0.0f; redcol[tid] = 0.0f; }

  // B staging: 16 x 1KB insts/round, wave w owns insts w*4..w*4+3.
  // Inst i covers rows [i*8, i*8+8): lane -> rc = i*8 + (lane>>3),
  // phys chunk = lane&7, logical chunk = (lane&7) ^ (rc&7) = (lane&7)^(lane>>3).
  const unsigned char* srcB[4]; unsigned char* dstB[4];
  {
    int rr = lane >> 3;
    int lc = (lane & 7) ^ rr;          // logical 16B chunk within 128B k-block
    #pragma unroll
    for (int seg = 0; seg < 4; ++seg) {
      int inst = wave * 4 + seg;
      srcB[seg] = Fb + (size_t)(col0 + inst * 8 + rr) * DIM + lc * 16;
      dstB[seg] = Blds + inst * 1024;  // linear LDS dest (DMA requirement)
    }
  }

  // A global fragment pointers: tile t -> panel (row0+wr0+t*16)>>4;
  // round kc adds kc*2048 (4 chunks x 512B); halves at +0 / +256.
  const unsigned char* agp[4];
  #pragma unroll
  for (int t = 0; t < 4; ++t)
    agp[t] = Fa + (size_t)((row0 + wr0 + t * 16) >> 4) * 8192 +
             quad * 512 + colid * 16;

  f32x4 acc[4][4];
  #pragma unroll
  for (int t = 0; t < 4; ++t)
    #pragma unroll
    for (int u = 0; u < 4; ++u) acc[t][u] = (f32x4){0.f, 0.f, 0.f, 0.f};

  for (int kc = 0; kc < 4; ++kc) {
    __syncthreads();                   // prior round's B reads done
    #pragma unroll
    for (int seg = 0; seg < 4; ++seg)
      async16(srcB[seg] + kc * 128, dstB[seg]);
    // A fragment loads (global, coalesced): L2 latency overlaps DMA drain.
    // Merged immediately into v8i32 so only av[4] (32 regs) crosses the
    // barrier.
    i32x8 av[4];
    #pragma unroll
    for (int t = 0; t < 4; ++t) {
      const unsigned char* ap = agp[t] + kc * 2048;
      i32x4 a0 = *reinterpret_cast<const i32x4*>(ap);
      i32x4 a1 = *reinterpret_cast<const i32x4*>(ap + 256);
      av[t] = __builtin_shufflevector(a0, a1, 0, 1, 2, 3, 4, 5, 6, 7);
    }
    __syncthreads();                   // drains DMA -> B tile visible

    // u-outer: ONE B fragment live at a time (8 regs), fed to 4 MFMAs.
    #pragma unroll
    for (int u = 0; u < 4; ++u) {
      // lane needs logical chunks {2q, 2q+1} of row rc = wc0+u*16+colid;
      // phys lo = 2q ^ (rc&7); hi chunk = lo ^ 1 (byte ^16; rc*128 bit4==0).
      int rc = wc0 + u * 16 + colid;
      int bo = rc * 128 + (((2 * quad) ^ (rc & 7)) << 4);
      i32x4 b0 = *reinterpret_cast<const i32x4*>(Blds + bo);
      i32x4 b1 = *reinterpret_cast<const i32x4*>(Blds + (bo ^ 16));
      i32x8 bv = __builtin_shufflevector(b0, b1, 0, 1, 2, 3, 4, 5, 6, 7);
      #pragma unroll
      for (int t = 0; t < 4; ++t)
        acc[t][u] = __builtin_amdgcn_mfma_scale_f32_16x16x128_f8f6f4(
            av[t], bv, acc[t][u],
            0 /*cbsz: fp8 e4m3*/, 0 /*blgp: fp8 e4m3*/,
            0, SCALE_ONE, 0, SCALE_ONE);
    }
  }

  // Epilogue. C/D layout: col = lane&15, row = quad*4 + reg (shape-determined,
  // identical to 16x16x32 — m89/m127-verified).
  float re[4][4];
  float ce[4];
  #pragma unroll
  for (int t = 0; t < 4; ++t)
    #pragma unroll
    for (int r = 0; r < 4; ++r) re[t][r] = 0.0f;
  #pragma unroll
  for (int u = 0; u < 4; ++u) ce[u] = 0.0f;

  #pragma unroll
  for (int t = 0; t < 4; ++t) {
    #pragma unroll
    for (int u = 0; u < 4; ++u) {
      f32x4 a = acc[t][u];
      const int gc = col0 + wc0 + u * 16 + colid;
      #pragma unroll
      for (int r = 0; r < 4; ++r) {
        int grow = row0 + wr0 + t * 16 + quad * 4 + r;
        float sim = a[r] * INV_T;
        float e = (gc > grow) ? __expf(sim) : 0.0f;  // strict upper triangle
        re[t][r] += e;
        ce[u] += e;
        if (gc == grow + HALF_N && grow < HALF_N) {
          pairsim[grow] = sim;         // unique writer per pair
          pairsim[gc] = sim;
        }
      }
    }
  }

  // Row sums: reduce across the 16 col-lanes, LDS-accumulate.
  #pragma unroll
  for (int t = 0; t < 4; ++t)
    #pragma unroll
    for (int r = 0; r < 4; ++r) {
      float v = re[t][r];
      v += __shfl_xor(v, 1); v += __shfl_xor(v, 2);
      v += __shfl_xor(v, 4); v += __shfl_xor(v, 8);
      if (colid == 0) atomicAdd(&redrow[wr0 + t * 16 + quad * 4 + r], v);
    }
  // Col sums: reduce across the 4 quads (this wave's 64 rows).
  #pragma unroll
  for (int u = 0; u < 4; ++u) {
    float v = ce[u];
    v += __shfl_xor(v, 16); v += __shfl_xor(v, 32);
    if (lane < 16) atomicAdd(&redcol[wc0 + u * 16 + colid], v);
  }
  __syncthreads();
  if (tid < 128) atomicAdd(&rowsum[row0 + tid], redrow[tid]);
  else           atomicAdd(&rowsum[col0 + tid - 128], redcol[tid - 128]);
}

// Kernel 3: loss partials. 32 blocks x 256 threads, one row each;
// per-wave reduce then one atomicAdd per wave into out (zeroed in kernel 1).
__global__ __launch_bounds__(256) void finalize_k(
    const float* __restrict__ rowsum, const float* __restrict__ pairsim,
    float* __restrict__ out) {
  int i = blockIdx.x * 256 + threadIdx.x;
  float local = logf(rowsum[i]) - pairsim[i];
  #pragma unroll
  for (int off = 1; off < 64; off <<= 1) local += __shfl_xor(local, off);
  if ((threadIdx.x & 63) == 0)
    atomicAdd(out, local * (1.0f / (float)NROWS));
}

extern "C" void kernel_launch(void* const* d_in, const int* in_sizes, int n_in,
                              void* d_out, int out_size, void* d_ws, size_t ws_size,
                              hipStream_t stream) {
  const float* f1 = (const float*)d_in[0];
  const float* f2 = (const float*)d_in[1];
  unsigned char* Fa = (unsigned char*)d_ws;                     // 4 MB fp8
  unsigned char* Fb = Fa + (size_t)NROWS * DIM;                 // 4 MB fp8
  float* rowsum = (float*)(Fb + (size_t)NROWS * DIM);
  float* pairsim = rowsum + NROWS;
  float* out = (float*)d_out;

  norm_cast_k<<<NROWS / 4, 256, 0, stream>>>(f1, f2, Fa, Fb, rowsum, out);
  sym_gemm_k<<<NBLOCKS, 256, 0, stream>>>(Fa, Fb, rowsum, pairsim);
  finalize_k<<<NROWS / 256, 256, 0, stream>>>(rowsum, pairsim, out);
}

// Round 4
// 108.596 us; speedup vs baseline: 2.3932x; 2.3932x over previous
//
#include <hip/hip_runtime.h>

#define NROWS 8192
#define HALF_N 4096
#define DIM 512
#define INV_T 10.0f
#define NRB 64              // number of 128-row blocks
#define NBLOCKS 2080        // 64*65/2 upper-triangle block pairs

typedef __attribute__((ext_vector_type(4))) float f32x4;
typedef __attribute__((ext_vector_type(2))) long long2v;

// async 16B global -> LDS (DMA). LDS dest is wave-uniform base + lane*16.
__device__ __forceinline__ void async16(const void* g, void* l) {
  __builtin_amdgcn_global_load_lds(
      (const __attribute__((address_space(1))) unsigned int*)g,
      (__attribute__((address_space(3))) unsigned int*)l, 16, 0, 0);
}

// Kernel 1: L2-normalize rows of [f1;f2] -> fp8 e4m3, written TWICE:
//  Fb: row-major, k-permuted within each 64B group (unit u -> pos
//      2*(u&3)+(u>>2)) — the B/LDS copy (R8-proven geometry).
//  Fa: fragment-major — panel p = row>>4 is 8 KB laid out as
//      [chunk c=0..31][row&15][16B], where chunk c holds k-units {c&3, (c&3)+4}
//      of k-group c>>2 (same pairing as Fb). A-fragment loads in the GEMM
//      become coalesced global b128 (quarter-wave = 256 B contiguous).
__global__ __launch_bounds__(256) void norm_cast_k(
    const float* __restrict__ f1, const float* __restrict__ f2,
    unsigned char* __restrict__ Fa, unsigned char* __restrict__ Fb,
    float* __restrict__ rowsum, float* __restrict__ out) {
  int wave = threadIdx.x >> 6;
  int lane = threadIdx.x & 63;
  int row = blockIdx.x * 4 + wave;
  const float* src = (row < HALF_N) ? (f1 + (size_t)row * DIM)
                                    : (f2 + (size_t)(row - HALF_N) * DIM);
  const float4* p = reinterpret_cast<const float4*>(src + lane * 8);
  float4 v0 = p[0];
  float4 v1 = p[1];
  float ss = v0.x*v0.x + v0.y*v0.y + v0.z*v0.z + v0.w*v0.w
           + v1.x*v1.x + v1.y*v1.y + v1.z*v1.z + v1.w*v1.w;
  #pragma unroll
  for (int off = 1; off < 64; off <<= 1) ss += __shfl_xor(ss, off);
  float scale = 1.0f / fmaxf(sqrtf(ss), 1e-12f);
  int lo = __builtin_amdgcn_cvt_pk_fp8_f32(v0.x * scale, v0.y * scale, 0, false);
  lo = __builtin_amdgcn_cvt_pk_fp8_f32(v0.z * scale, v0.w * scale, lo, true);
  int hi = __builtin_amdgcn_cvt_pk_fp8_f32(v1.x * scale, v1.y * scale, 0, false);
  hi = __builtin_amdgcn_cvt_pk_fp8_f32(v1.z * scale, v1.w * scale, hi, true);
  int2 val = make_int2(lo, hi);
  int u = lane & 7;                     // k-unit within 64B group
  int g = lane >> 3;                    // k-group (0..7)
  // Fb: row-major k-permuted
  int pos = 2 * (u & 3) + (u >> 2);
  *reinterpret_cast<int2*>(Fb + (size_t)row * DIM + g * 64 + pos * 8) = val;
  // Fa: fragment-major
  int chunk = g * 4 + (u & 3);          // global 16B chunk index (0..31)
  int slot = u >> 2;                    // which 8B half of the chunk
  *reinterpret_cast<int2*>(Fa + (size_t)(row >> 4) * 8192 + chunk * 256 +
                           (row & 15) * 16 + slot * 8) = val;
  if (lane == 0) rowsum[row] = 0.0f;
  if (blockIdx.x == 0 && threadIdx.x == 0) out[0] = 0.0f;
}

// Kernel 2: symmetric upper-triangle sim GEMM (fp8 e4m3, NON-scaled
// mfma_f32_16x16x32 — the MX-scaled builtin's HIP lowering spills its v8i32
// operands through scratch on this ROCm: R1-R3 all showed identical 84 VGPR +
// ~290 MB scratch WRITE_SIZE regardless of source structure. Do not retry.)
// New vs R0: DOUBLE-BUFFERED B tile + one barrier per round (T3 minimum
// 2-phase recipe). Round kc issues the DMA for round kc+1 and prefetches
// A(kc+1) into registers, so the end-of-round barrier drain waits on loads
// that had a full round of MFMA/ds_read to cover their latency. R0 issued
// and drained the DMA within the same round: 8x exposed global->LDS latency.
__global__ __launch_bounds__(256, 3) void sym_gemm_k(
    const unsigned char* __restrict__ Fa, const unsigned char* __restrict__ Fb,
    float* __restrict__ rowsum, float* __restrict__ pairsim) {
  // XCD-contiguous remap: each XCD (bx%8) gets a contiguous 260-block range
  int bx = blockIdx.x;
  int gbx = (bx & 7) * (NBLOCKS / 8) + (bx >> 3);
  int rb = 0, rem = gbx;
  while (rem >= NRB - rb) { rem -= NRB - rb; ++rb; }
  const int cb = rb + rem;
  const int row0 = rb * 128, col0 = cb * 128;

  const int tid = threadIdx.x;
  const int wave = tid >> 6;
  const int lane = tid & 63;
  const int quad = lane >> 4;
  const int colid = lane & 15;
  const int wr0 = (wave >> 1) * 64;   // wave's row offset within tile
  const int wc0 = (wave & 1) * 64;    // wave's col offset within tile

  // B LDS tile, double-buffered: 2 x (128 rows x 64 B). Physical 16B chunk =
  // logical ^ ((row>>1)&3) -> conflict-free b128 reads (R8-proven).
  __shared__ __align__(16) unsigned char Blds[2][128 * 64];
  __shared__ float redrow[128];
  __shared__ float redcol[128];

  if (tid < 128) { redrow[tid] = 0.0f; redcol[tid] = 0.0f; }

  // B staging: 8 x 1KB insts/round, wave w owns insts {w, w+4}.
  // Inst i covers rows [i*16, i*16+16): lane -> r = i*16 + (lane>>2),
  // phys chunk = lane&3, global logical chunk = (lane&3) ^ ((r>>1)&3).
  const unsigned char* srcB[2]; int dstO[2];
  #pragma unroll
  for (int seg = 0; seg < 2; ++seg) {
    int inst = wave + seg * 4;
    int r = inst * 16 + (lane >> 2);
    int c = (lane & 3) ^ ((r >> 1) & 3);
    srcB[seg] = Fb + (size_t)(col0 + r) * DIM + c * 16;
    dstO[seg] = inst * 1024;          // 16 rows x 64 B per inst
  }

  // A global fragment pointers: tile t -> panel (row0+wr0+t*16)>>4;
  // round kc, quad q -> chunk kc*4+q; lane colid -> row-in-panel.
  // Quarter-wave reads 16 x 16B = 256 B contiguous (coalesced, L2-hit).
  const unsigned char* agp[4];
  #pragma unroll
  for (int t = 0; t < 4; ++t)
    agp[t] = Fa + (size_t)((row0 + wr0 + t * 16) >> 4) * 8192 +
             quad * 256 + colid * 16;

  // B fragment LDS byte offsets: logical chunk = quad; phys = quad^((rc>>1)&3).
  int boff[4];
  #pragma unroll
  for (int t = 0; t < 4; ++t) {
    int rc = wc0 + t * 16 + colid;
    boff[t] = rc * 64 + ((quad ^ ((rc >> 1) & 3)) << 4);
  }

  f32x4 acc[4][4];
  #pragma unroll
  for (int t = 0; t < 4; ++t)
    #pragma unroll
    for (int u = 0; u < 4; ++u) acc[t][u] = (f32x4){0.f, 0.f, 0.f, 0.f};

  // Prologue: stage round 0 into buf 0, load A(0); barrier drains both.
  #pragma unroll
  for (int seg = 0; seg < 2; ++seg)
    async16(srcB[seg], &Blds[0][0] + dstO[seg]);
  long2v afc[4];
  #pragma unroll
  for (int t = 0; t < 4; ++t)
    afc[t] = *reinterpret_cast<const long2v*>(agp[t]);
  __syncthreads();

  #pragma unroll
  for (int kc = 0; kc < 8; ++kc) {
    const int cur = kc & 1;
    // Issue NEXT round's staging + A prefetch first: a full round of
    // ds_read+MFMA covers their latency before the end-of-round drain.
    if (kc < 7) {
      #pragma unroll
      for (int seg = 0; seg < 2; ++seg)
        async16(srcB[seg] + (kc + 1) * 64, &Blds[cur ^ 1][0] + dstO[seg]);
    }
    long2v afn[4];
    if (kc < 7) {
      #pragma unroll
      for (int t = 0; t < 4; ++t)
        afn[t] = *reinterpret_cast<const long2v*>(agp[t] + (kc + 1) * 1024);
    }

    long2v bf[4];
    #pragma unroll
    for (int u = 0; u < 4; ++u)
      bf[u] = *reinterpret_cast<const long2v*>(&Blds[cur][0] + boff[u]);
    #pragma unroll
    for (int s = 0; s < 2; ++s)
      #pragma unroll
      for (int t = 0; t < 4; ++t)
        #pragma unroll
        for (int u = 0; u < 4; ++u)
          acc[t][u] = __builtin_amdgcn_mfma_f32_16x16x32_fp8_fp8(
              afc[t][s], bf[u][s], acc[t][u], 0, 0, 0);

    // One barrier per round: (a) all waves' reads of buf[cur] done, so it
    // can be re-staged next round; (b) implicit vmcnt(0) drain makes the
    // just-staged buf[cur^1] visible to all waves.
    __syncthreads();
    if (kc < 7) {
      #pragma unroll
      for (int t = 0; t < 4; ++t) afc[t] = afn[t];
    }
  }

  // Epilogue. C/D layout: col = lane&15, row = quad*4 + reg (m89-verified,
  // dtype-independent on gfx950).
  float re[4][4];
  float ce[4];
  #pragma unroll
  for (int t = 0; t < 4; ++t)
    #pragma unroll
    for (int r = 0; r < 4; ++r) re[t][r] = 0.0f;
  #pragma unroll
  for (int u = 0; u < 4; ++u) ce[u] = 0.0f;

  #pragma unroll
  for (int t = 0; t < 4; ++t) {
    #pragma unroll
    for (int u = 0; u < 4; ++u) {
      f32x4 a = acc[t][u];
      const int gc = col0 + wc0 + u * 16 + colid;
      #pragma unroll
      for (int r = 0; r < 4; ++r) {
        int grow = row0 + wr0 + t * 16 + quad * 4 + r;
        float sim = a[r] * INV_T;
        float e = (gc > grow) ? __expf(sim) : 0.0f;  // strict upper triangle
        re[t][r] += e;
        ce[u] += e;
        if (gc == grow + HALF_N && grow < HALF_N) {
          pairsim[grow] = sim;         // unique writer per pair
          pairsim[gc] = sim;
        }
      }
    }
  }

  // Row sums: reduce across the 16 col-lanes, LDS-accumulate.
  #pragma unroll
  for (int t = 0; t < 4; ++t)
    #pragma unroll
    for (int r = 0; r < 4; ++r) {
      float v = re[t][r];
      v += __shfl_xor(v, 1); v += __shfl_xor(v, 2);
      v += __shfl_xor(v, 4); v += __shfl_xor(v, 8);
      if (colid == 0) atomicAdd(&redrow[wr0 + t * 16 + quad * 4 + r], v);
    }
  // Col sums: reduce across the 4 quads (this wave's 64 rows).
  #pragma unroll
  for (int u = 0; u < 4; ++u) {
    float v = ce[u];
    v += __shfl_xor(v, 16); v += __shfl_xor(v, 32);
    if (lane < 16) atomicAdd(&redcol[wc0 + u * 16 + colid], v);
  }
  __syncthreads();
  if (tid < 128) atomicAdd(&rowsum[row0 + tid], redrow[tid]);
  else           atomicAdd(&rowsum[col0 + tid - 128], redcol[tid - 128]);
}

// Kernel 3: loss partials. 32 blocks x 256 threads, one row each;
// per-wave reduce then one atomicAdd per wave into out (zeroed in kernel 1).
__global__ __launch_bounds__(256) void finalize_k(
    const float* __restrict__ rowsum, const float* __restrict__ pairsim,
    float* __restrict__ out) {
  int i = blockIdx.x * 256 + threadIdx.x;
  float local = logf(rowsum[i]) - pairsim[i];
  #pragma unroll
  for (int off = 1; off < 64; off <<= 1) local += __shfl_xor(local, off);
  if ((threadIdx.x & 63) == 0)
    atomicAdd(out, local * (1.0f / (float)NROWS));
}

extern "C" void kernel_launch(void* const* d_in, const int* in_sizes, int n_in,
                              void* d_out, int out_size, void* d_ws, size_t ws_size,
                              hipStream_t stream) {
  const float* f1 = (const float*)d_in[0];
  const float* f2 = (const float*)d_in[1];
  unsigned char* Fa = (unsigned char*)d_ws;                     // 4 MB fp8
  unsigned char* Fb = Fa + (size_t)NROWS * DIM;                 // 4 MB fp8
  float* rowsum = (float*)(Fb + (size_t)NROWS * DIM);
  float* pairsim = rowsum + NROWS;
  float* out = (float*)d_out;

  norm_cast_k<<<NROWS / 4, 256, 0, stream>>>(f1, f2, Fa, Fb, rowsum, out);
  sym_gemm_k<<<NBLOCKS, 256, 0, stream>>>(Fa, Fb, rowsum, pairsim);
  finalize_k<<<NROWS / 256, 256, 0, stream>>>(rowsum, pairsim, out);
}